// Round 10
// baseline (784.299 us; speedup 1.0000x reference)
//
#include <hip/hip_runtime.h>
#include <hip/hip_bf16.h>

typedef _Float16 half4v __attribute__((ext_vector_type(4)));
typedef _Float16 half8v __attribute__((ext_vector_type(8)));
typedef float float4v __attribute__((ext_vector_type(4)));
typedef float float16v __attribute__((ext_vector_type(16)));

#define L_SEQ 2048
#define EMB 1024
#define NH 16
#define DKV 64

__device__ inline void gll16(const void* g, void* l) {
  __builtin_amdgcn_global_load_lds((const __attribute__((address_space(1))) void*)g,
                                   (__attribute__((address_space(3))) void*)l, 16, 0, 0);
}

// ---------------------------------------------------------------------------
// Kernel A: cast X fp32 -> f16 (4096x1024), 8 elems/thread
// ---------------------------------------------------------------------------
__global__ __launch_bounds__(256) void xcast_kernel(const float* __restrict__ X,
                                                    _Float16* __restrict__ X16) {
  size_t i = ((size_t)blockIdx.x * 256 + threadIdx.x) * 8;
  float4v v0 = *(const float4v*)(X + i);
  float4v v1 = *(const float4v*)(X + i + 4);
  half8v h;
  h[0] = (_Float16)v0[0]; h[1] = (_Float16)v0[1]; h[2] = (_Float16)v0[2]; h[3] = (_Float16)v0[3];
  h[4] = (_Float16)v1[0]; h[5] = (_Float16)v1[1]; h[6] = (_Float16)v1[2]; h[7] = (_Float16)v1[3];
  *(half8v*)(X16 + i) = h;
}

// ---------------------------------------------------------------------------
// Kernel B: pack + transpose + cast W_qkv (fp32 [1024][3072]) -> Wt (f16 [2048][1024])
// ---------------------------------------------------------------------------
__global__ __launch_bounds__(256) void wpack_kernel(const float* __restrict__ W,
                                                    _Float16* __restrict__ Wt) {
  __shared__ float tile[32][33];
  int n0 = blockIdx.x * 32;
  int k0 = blockIdx.y * 32;
  int h = n0 >> 7;
  int wc = h * 192 + (n0 & 127);
  int tx = threadIdx.x & 31;
  int ty = threadIdx.x >> 5;
#pragma unroll
  for (int i = 0; i < 4; ++i) {
    int k = ty + i * 8;
    tile[k][tx] = W[(size_t)(k0 + k) * 3072 + wc + tx];
  }
  __syncthreads();
#pragma unroll
  for (int i = 0; i < 4; ++i) {
    int n = ty + i * 8;
    Wt[(size_t)(n0 + n) * 1024 + k0 + tx] = (_Float16)tile[tx][n];
  }
}

// ---------------------------------------------------------------------------
// Kernel C (v4, DIAG x16): BM=128, BN=64, BK=64, conflict-free XOR-granule
// LDS (from v3), LINEAR id map (as R8's v2, isolating the LDS variable).
// blockIdx.y = replica (identical writes). A/B vs R8: 490us, 5e7 conflicts.
// ---------------------------------------------------------------------------
__global__ __launch_bounds__(256, 4) void qk_gemm_kernel(const _Float16* __restrict__ X16,
                                                         const _Float16* __restrict__ Wt,
                                                         const float* __restrict__ bias,
                                                         _Float16* __restrict__ Qh,
                                                         _Float16* __restrict__ Kh) {
  __shared__ _Float16 As[128 * 64];  // 16 KB
  __shared__ _Float16 Bs[64 * 64];   // 8 KB
  int id = blockIdx.x;
  int n0 = (id & 31) * 64;
  int m0 = (id >> 5) * 128;
  int t = threadIdx.x;
  int l = t & 63;
  int wv = t >> 6;
  int wm = wv >> 1, wn = wv & 1;
  int cl = l & 15, hi = l >> 4;
  float4v acc[4][2] = {};
  for (int k0 = 0; k0 < 1024; k0 += 64) {
#pragma unroll
    for (int c = 0; c < 4; ++c) {
      int gi = (wv * 4 + c) * 64 + l;
      int r_ = gi >> 3, s_ = gi & 7;
      gll16(X16 + (size_t)(m0 + r_) * 1024 + k0 + 8 * (s_ ^ (r_ & 7)), &As[(wv * 4 + c) * 512]);
    }
#pragma unroll
    for (int c = 0; c < 2; ++c) {
      int gi = (wv * 2 + c) * 64 + l;
      int r_ = gi >> 3, s_ = gi & 7;
      gll16(Wt + (size_t)(n0 + r_) * 1024 + k0 + 8 * (s_ ^ (r_ & 7)), &Bs[(wv * 2 + c) * 512]);
    }
    __syncthreads();
#pragma unroll
    for (int kh = 0; kh < 2; ++kh) {
      int g = kh * 4 + hi;  // logical granule = k/8
      half8v a[4], b[2];
#pragma unroll
      for (int mt = 0; mt < 4; ++mt) {
        int row = wm * 64 + mt * 16 + cl;
        a[mt] = *(const half8v*)(&As[row * 64 + 8 * (g ^ (row & 7))]);
      }
#pragma unroll
      for (int nt = 0; nt < 2; ++nt) {
        int row = wn * 32 + nt * 16 + cl;
        b[nt] = *(const half8v*)(&Bs[row * 64 + 8 * (g ^ (row & 7))]);
      }
#pragma unroll
      for (int mt = 0; mt < 4; ++mt)
#pragma unroll
        for (int nt = 0; nt < 2; ++nt)
          acc[mt][nt] = __builtin_amdgcn_mfma_f32_16x16x32_f16(a[mt], b[nt], acc[mt][nt], 0, 0, 0);
    }
    __syncthreads();
  }
#pragma unroll
  for (int mt = 0; mt < 4; ++mt) {
#pragma unroll
    for (int nt = 0; nt < 2; ++nt) {
      int n_g = n0 + wn * 32 + nt * 16 + cl;
      int hh = n_g >> 7, rr = n_g & 127;
      float bv = bias[hh * 192 + rr];
      _Float16* dstbase = (rr < 64) ? Qh : Kh;
      int d = rr & 63;
#pragma unroll
      for (int r = 0; r < 4; ++r) {
        int row_g = m0 + wm * 64 + mt * 16 + hi * 4 + r;
        int bb = row_g >> 11, lr = row_g & 2047;
        dstbase[(((size_t)bb * NH + hh) * L_SEQ + lr) * DKV + d] = (_Float16)(acc[mt][nt][r] + bv);
      }
    }
  }
}

// ---------------------------------------------------------------------------
// Kernel D (v6.1, DIAG x4): v6 + counted-vmcnt barrier in pass 2 (T4):
// s_waitcnt vmcnt(32) + raw s_barrier lets each step's 32 NT stores stay in
// flight across the dbuf barrier (staging loads are older -> retired; only
// the newest 32 ops, the stores, may remain). A/B vs R8: ~397us inferred.
// ---------------------------------------------------------------------------
__global__ __launch_bounds__(256, 4) void attn_softmax_kernel(const _Float16* __restrict__ Qh,
                                                              const _Float16* __restrict__ Kh,
                                                              float* __restrict__ out) {
  __shared__ _Float16 Ks[2][128 * 64];  // 32 KB dbuf, granule-swizzled rows
  __shared__ float sums[4][32];
  int id = blockIdx.x & 1023;  // replicas: blockIdx.x>>10 in {0..3}
  int xcd = id & 7;
  int rest = id >> 3;
  int rb = rest & 31;
  int bh = ((rest >> 5) << 3) + xcd;  // bijective XCD swizzle
  int t = threadIdx.x;
  int l = t & 63;
  int wv = t >> 6;
  int lj = l & 31;
  int hk = l >> 5;
  int qh = wv & 1;
  int jh = wv >> 1;
  int qbase = rb * 64;
  const _Float16* Qb = Qh + ((size_t)bh * L_SEQ + qbase) * DKV;
  const _Float16* Kb = Kh + (size_t)bh * L_SEQ * DKV;
  const float SC = 0.18033688011112042f;  // log2(e)/sqrt(64)

  half8v bq[4];
#pragma unroll
  for (int ks = 0; ks < 4; ++ks)
    bq[ks] = *(const half8v*)(Qb + (size_t)(qh * 32 + lj) * DKV + ks * 16 + hk * 8);

#define STAGE(bufi, j0)                                                     \
  {                                                                         \
    _Pragma("unroll") for (int c = 0; c < 4; ++c) {                         \
      int gi = (wv * 4 + c) * 64 + l;                                       \
      int r_ = gi >> 3, s_ = gi & 7;                                        \
      gll16(Kb + (size_t)((j0) + r_) * DKV + 8 * (s_ ^ (r_ & 7)),           \
            &Ks[bufi][(wv * 4 + c) * 512]);                                 \
    }                                                                       \
  }

  // ---- Pass 1: row sums.  mfma(A=K, B=Q): D col = q (lj), rows = j ----
  float lsum = 0.f;
  int buf = 0;
  STAGE(0, 0);
  __syncthreads();
  for (int s = 0; s < 16; ++s) {
    if (s + 1 < 16) STAGE(buf ^ 1, (s + 1) * 128);
#pragma unroll
    for (int q2 = 0; q2 < 2; ++q2) {
      int jq = jh * 2 + q2;
      int krow = jq * 32 + lj;
      half8v bk[4];
#pragma unroll
      for (int ks = 0; ks < 4; ++ks)
        bk[ks] = *(const half8v*)(&Ks[buf][krow * 64 + 8 * ((2 * ks + hk) ^ (krow & 7))]);
      float16v acc = {};
#pragma unroll
      for (int ks = 0; ks < 4; ++ks)
        acc = __builtin_amdgcn_mfma_f32_32x32x16_f16(bk[ks], bq[ks], acc, 0, 0, 0);
#pragma unroll
      for (int i = 0; i < 16; ++i) lsum += __builtin_amdgcn_exp2f(acc[i] * SC);
    }
    __syncthreads();
    buf ^= 1;
  }
  lsum += __shfl_xor(lsum, 32);
  if (l < 32) sums[wv][lj] = lsum;
  __syncthreads();

  float cc[16];
#pragma unroll
  for (int i = 0; i < 16; ++i) {
    int qo = (i & 3) + 8 * (i >> 2) + 4 * hk;
    cc[i] = -__log2f(sums[qh][qo] + sums[qh + 2][qo]);
  }

  // ---- Pass 2: recompute, mfma(A=Q, B=K): D col = j (lj), rows = q ----
  size_t orow0 = ((size_t)bh * L_SEQ + qbase + qh * 32) * L_SEQ;
  STAGE(0, 0);
  __syncthreads();
  buf = 0;
  for (int s = 0; s < 16; ++s) {
    if (s + 1 < 16) STAGE(buf ^ 1, (s + 1) * 128);
#pragma unroll
    for (int q2 = 0; q2 < 2; ++q2) {
      int jq = jh * 2 + q2;
      int krow = jq * 32 + lj;
      half8v bk[4];
#pragma unroll
      for (int ks = 0; ks < 4; ++ks)
        bk[ks] = *(const half8v*)(&Ks[buf][krow * 64 + 8 * ((2 * ks + hk) ^ (krow & 7))]);
      float16v acc = {};
#pragma unroll
      for (int ks = 0; ks < 4; ++ks)
        acc = __builtin_amdgcn_mfma_f32_32x32x16_f16(bq[ks], bk[ks], acc, 0, 0, 0);
      size_t col = (size_t)s * 128 + jq * 32 + lj;
#pragma unroll
      for (int i = 0; i < 16; ++i) {
        float p = __builtin_amdgcn_exp2f(acc[i] * SC + cc[i]);
        int qo = (i & 3) + 8 * (i >> 2) + 4 * hk;
        __builtin_nontemporal_store(p, out + orow0 + (size_t)qo * L_SEQ + col);
      }
    }
    // counted-vmcnt barrier: staging (issued before the 32 stores) retired;
    // the newest <=32 ops (this step's stores) may stay in flight.
    asm volatile("s_waitcnt vmcnt(32)" ::: "memory");
    __builtin_amdgcn_s_barrier();
    __builtin_amdgcn_sched_barrier(0);
    buf ^= 1;
  }
#undef STAGE
}

// ---------------------------------------------------------------------------
extern "C" void kernel_launch(void* const* d_in, const int* in_sizes, int n_in,
                              void* d_out, int out_size, void* d_ws, size_t ws_size,
                              hipStream_t stream) {
  const float* X = (const float*)d_in[0];
  const float* W = (const float*)d_in[1];
  const float* bias = (const float*)d_in[2];
  float* out = (float*)d_out;
  char* ws = (char*)d_ws;
  _Float16* Wt = (_Float16*)ws;                       // 4 MB
  _Float16* Qh = (_Float16*)(ws + (4ull << 20));      // 8 MB
  _Float16* Kh = (_Float16*)(ws + (12ull << 20));     // 8 MB
  _Float16* X16 = (_Float16*)(ws + (20ull << 20));    // 8 MB (total 28 MB)

  xcast_kernel<<<2048, 256, 0, stream>>>(X, X16);
  wpack_kernel<<<dim3(64, 32), 256, 0, stream>>>(W, Wt);
  // DIAG x16 (blockIdx.y = replica): apples-to-apples vs R8's 490us/5e7-conflict dispatch.
  qk_gemm_kernel<<<dim3(1024, 16), 256, 0, stream>>>(X16, Wt, bias, Qh, Kh);
  // DIAG x4: apples-to-apples vs R8's ~397us inferred attn dispatch.
  attn_softmax_kernel<<<4096, 256, 0, stream>>>(Qh, Kh, out);
}

// Round 11
// 168.713 us; speedup vs baseline: 4.6487x; 4.6487x over previous
//
#include <hip/hip_runtime.h>
#include <hip/hip_bf16.h>

typedef _Float16 half4v __attribute__((ext_vector_type(4)));
typedef _Float16 half8v __attribute__((ext_vector_type(8)));
typedef float float4v __attribute__((ext_vector_type(4)));
typedef float float16v __attribute__((ext_vector_type(16)));

#define L_SEQ 2048
#define EMB 1024
#define NH 16
#define DKV 64

__device__ inline void gll16(const void* g, void* l) {
  __builtin_amdgcn_global_load_lds((const __attribute__((address_space(1))) void*)g,
                                   (__attribute__((address_space(3))) void*)l, 16, 0, 0);
}

// ---------------------------------------------------------------------------
// Kernel A: cast X fp32 -> f16 (4096x1024), 8 elems/thread
// ---------------------------------------------------------------------------
__global__ __launch_bounds__(256) void xcast_kernel(const float* __restrict__ X,
                                                    _Float16* __restrict__ X16) {
  size_t i = ((size_t)blockIdx.x * 256 + threadIdx.x) * 8;
  float4v v0 = *(const float4v*)(X + i);
  float4v v1 = *(const float4v*)(X + i + 4);
  half8v h;
  h[0] = (_Float16)v0[0]; h[1] = (_Float16)v0[1]; h[2] = (_Float16)v0[2]; h[3] = (_Float16)v0[3];
  h[4] = (_Float16)v1[0]; h[5] = (_Float16)v1[1]; h[6] = (_Float16)v1[2]; h[7] = (_Float16)v1[3];
  *(half8v*)(X16 + i) = h;
}

// ---------------------------------------------------------------------------
// Kernel B: pack + transpose + cast W_qkv (fp32 [1024][3072]) -> Wt (f16 [2048][1024])
// ---------------------------------------------------------------------------
__global__ __launch_bounds__(256) void wpack_kernel(const float* __restrict__ W,
                                                    _Float16* __restrict__ Wt) {
  __shared__ float tile[32][33];
  int n0 = blockIdx.x * 32;
  int k0 = blockIdx.y * 32;
  int h = n0 >> 7;
  int wc = h * 192 + (n0 & 127);
  int tx = threadIdx.x & 31;
  int ty = threadIdx.x >> 5;
#pragma unroll
  for (int i = 0; i < 4; ++i) {
    int k = ty + i * 8;
    tile[k][tx] = W[(size_t)(k0 + k) * 3072 + wc + tx];
  }
  __syncthreads();
#pragma unroll
  for (int i = 0; i < 4; ++i) {
    int n = ty + i * 8;
    Wt[(size_t)(n0 + n) * 1024 + k0 + tx] = (_Float16)tile[tx][n];
  }
}

// ---------------------------------------------------------------------------
// Kernel C (v3): Q/K projection GEMM. BM=128, BN=64, BK=64; 1024 blocks
// (4/CU). Conflict-free XOR-granule LDS (validated R10: 30.6->21.1 us/copy).
// ---------------------------------------------------------------------------
__global__ __launch_bounds__(256, 4) void qk_gemm_kernel(const _Float16* __restrict__ X16,
                                                         const _Float16* __restrict__ Wt,
                                                         const float* __restrict__ bias,
                                                         _Float16* __restrict__ Qh,
                                                         _Float16* __restrict__ Kh) {
  __shared__ _Float16 As[128 * 64];  // 16 KB
  __shared__ _Float16 Bs[64 * 64];   // 8 KB
  int id = blockIdx.x;
  int xcd = id & 7;
  int rest = id >> 3;
  int n0 = (xcd * 4 + (rest & 3)) * 64;
  int m0 = (rest >> 2) * 128;
  int t = threadIdx.x;
  int l = t & 63;
  int wv = t >> 6;
  int wm = wv >> 1, wn = wv & 1;
  int cl = l & 15, hi = l >> 4;
  float4v acc[4][2] = {};
  for (int k0 = 0; k0 < 1024; k0 += 64) {
#pragma unroll
    for (int c = 0; c < 4; ++c) {
      int gi = (wv * 4 + c) * 64 + l;
      int r_ = gi >> 3, s_ = gi & 7;
      gll16(X16 + (size_t)(m0 + r_) * 1024 + k0 + 8 * (s_ ^ (r_ & 7)), &As[(wv * 4 + c) * 512]);
    }
#pragma unroll
    for (int c = 0; c < 2; ++c) {
      int gi = (wv * 2 + c) * 64 + l;
      int r_ = gi >> 3, s_ = gi & 7;
      gll16(Wt + (size_t)(n0 + r_) * 1024 + k0 + 8 * (s_ ^ (r_ & 7)), &Bs[(wv * 2 + c) * 512]);
    }
    __syncthreads();
#pragma unroll
    for (int kh = 0; kh < 2; ++kh) {
      int g = kh * 4 + hi;
      half8v a[4], b[2];
#pragma unroll
      for (int mt = 0; mt < 4; ++mt) {
        int row = wm * 64 + mt * 16 + cl;
        a[mt] = *(const half8v*)(&As[row * 64 + 8 * (g ^ (row & 7))]);
      }
#pragma unroll
      for (int nt = 0; nt < 2; ++nt) {
        int row = wn * 32 + nt * 16 + cl;
        b[nt] = *(const half8v*)(&Bs[row * 64 + 8 * (g ^ (row & 7))]);
      }
#pragma unroll
      for (int mt = 0; mt < 4; ++mt)
#pragma unroll
        for (int nt = 0; nt < 2; ++nt)
          acc[mt][nt] = __builtin_amdgcn_mfma_f32_16x16x32_f16(a[mt], b[nt], acc[mt][nt], 0, 0, 0);
    }
    __syncthreads();
  }
#pragma unroll
  for (int mt = 0; mt < 4; ++mt) {
#pragma unroll
    for (int nt = 0; nt < 2; ++nt) {
      int n_g = n0 + wn * 32 + nt * 16 + cl;
      int hh = n_g >> 7, rr = n_g & 127;
      float bv = bias[hh * 192 + rr];
      _Float16* dstbase = (rr < 64) ? Qh : Kh;
      int d = rr & 63;
#pragma unroll
      for (int r = 0; r < 4; ++r) {
        int row_g = m0 + wm * 64 + mt * 16 + hi * 4 + r;
        int bb = row_g >> 11, lr = row_g & 2047;
        dstbase[(((size_t)bb * NH + hh) * L_SEQ + lr) * DKV + d] = (_Float16)(acc[mt][nt][r] + bv);
      }
    }
  }
}

// ---------------------------------------------------------------------------
// Kernel D (v8): barrier-free 2-slab pipelined softmax.
// Block = 64 q (slabs A,B of 32 q) of one (b,h). K fragments are per-lane
// GLOBAL loads (L2-resident XCD-pinned panel), 2-step register prefetch --
// no LDS staging, no per-step barriers, so NT stores stream continuously.
// Phase1: sums(A). Phase2: stores(A)+sums(B) off the same kc registers.
// Phase3: stores(B). Only the two sum-reduces use __syncthreads.
// Symmetric 32x32x16 f16 fragments: same kc serves A- and B-operand roles.
// ---------------------------------------------------------------------------
__global__ __launch_bounds__(256, 3) void attn_softmax_kernel(const _Float16* __restrict__ Qh,
                                                              const _Float16* __restrict__ Kh,
                                                              float* __restrict__ out) {
  __shared__ float red[4][32];
  __shared__ float ccs[2][32];
  int id = blockIdx.x;
  int xcd = id & 7;
  int rest = id >> 3;
  int rb = rest & 31;
  int bh = ((rest >> 5) << 3) + xcd;  // bijective XCD swizzle: same-bh -> same XCD
  int t = threadIdx.x;
  int l = t & 63;
  int wv = t >> 6;
  int lj = l & 31;
  int hk = l >> 5;
  const float SC = 0.18033688011112042f;  // log2(e)/sqrt(64)
  const _Float16* Qb = Qh + ((size_t)bh * L_SEQ + rb * 64) * DKV;
  const _Float16* Kl = Kh + (size_t)bh * L_SEQ * DKV + (size_t)(wv * 32 + lj) * DKV + hk * 8;

  half8v qa[4], qb[4];
#pragma unroll
  for (int ks = 0; ks < 4; ++ks) {
    qa[ks] = *(const half8v*)(Qb + (size_t)lj * DKV + ks * 16 + hk * 8);
    qb[ks] = *(const half8v*)(Qb + (size_t)(32 + lj) * DKV + ks * 16 + hk * 8);
  }

#define KLOAD(dst, s)                                                        \
  _Pragma("unroll") for (int ks = 0; ks < 4; ++ks)                           \
      dst[ks] = *(const half8v*)(Kl + (size_t)(s) * 8192 + ks * 16);
#define ROT()                                                                \
  _Pragma("unroll") for (int ks = 0; ks < 4; ++ks) {                         \
    k0[ks] = k1[ks]; k1[ks] = k2[ks];                                        \
  }

  half8v k0[4], k1[4], k2[4];

  // ---- Phase 1: sums(A). mfma(K,Q): D col = q = lj ----
  float lsum = 0.f;
  KLOAD(k0, 0);
  KLOAD(k1, 1);
#pragma unroll 2
  for (int s = 0; s < 16; ++s) {
    if (s + 2 < 16) KLOAD(k2, s + 2);
    float16v acc = {};
#pragma unroll
    for (int ks = 0; ks < 4; ++ks)
      acc = __builtin_amdgcn_mfma_f32_32x32x16_f16(k0[ks], qa[ks], acc, 0, 0, 0);
#pragma unroll
    for (int i = 0; i < 16; ++i) lsum += __builtin_amdgcn_exp2f(acc[i] * SC);
    ROT();
  }
  lsum += __shfl_xor(lsum, 32);
  if (l < 32) red[wv][lj] = lsum;
  __syncthreads();
  if (t < 32) ccs[0][t] = -__log2f(red[0][t] + red[1][t] + red[2][t] + red[3][t]);
  __syncthreads();
  float ccA[16];
#pragma unroll
  for (int i = 0; i < 16; ++i) ccA[i] = ccs[0][(i & 3) + 8 * (i >> 2) + 4 * hk];

  // ---- Phase 2: stores(A) + sums(B), same kc registers ----
  float* outA = out + ((size_t)bh * L_SEQ + rb * 64 + 4 * hk) * L_SEQ + wv * 32 + lj;
  float lsumB = 0.f;
  KLOAD(k0, 0);
  KLOAD(k1, 1);
#pragma unroll 2
  for (int s = 0; s < 16; ++s) {
    if (s + 2 < 16) KLOAD(k2, s + 2);
    float16v accS = {};
#pragma unroll
    for (int ks = 0; ks < 4; ++ks)
      accS = __builtin_amdgcn_mfma_f32_32x32x16_f16(qa[ks], k0[ks], accS, 0, 0, 0);
#pragma unroll
    for (int i = 0; i < 16; ++i) {
      float p = __builtin_amdgcn_exp2f(accS[i] * SC + ccA[i]);
      __builtin_nontemporal_store(p, outA + (size_t)((i & 3) + 8 * (i >> 2)) * L_SEQ + s * 128);
    }
    float16v accB = {};
#pragma unroll
    for (int ks = 0; ks < 4; ++ks)
      accB = __builtin_amdgcn_mfma_f32_32x32x16_f16(k0[ks], qb[ks], accB, 0, 0, 0);
#pragma unroll
    for (int i = 0; i < 16; ++i) lsumB += __builtin_amdgcn_exp2f(accB[i] * SC);
    ROT();
  }
  lsumB += __shfl_xor(lsumB, 32);
  if (l < 32) red[wv][lj] = lsumB;
  __syncthreads();
  if (t < 32) ccs[1][t] = -__log2f(red[0][t] + red[1][t] + red[2][t] + red[3][t]);
  __syncthreads();
  float ccB[16];
#pragma unroll
  for (int i = 0; i < 16; ++i) ccB[i] = ccs[1][(i & 3) + 8 * (i >> 2) + 4 * hk];

  // ---- Phase 3: stores(B) ----
  float* outB = outA + (size_t)32 * L_SEQ;
  KLOAD(k0, 0);
  KLOAD(k1, 1);
#pragma unroll 2
  for (int s = 0; s < 16; ++s) {
    if (s + 2 < 16) KLOAD(k2, s + 2);
    float16v accS = {};
#pragma unroll
    for (int ks = 0; ks < 4; ++ks)
      accS = __builtin_amdgcn_mfma_f32_32x32x16_f16(qb[ks], k0[ks], accS, 0, 0, 0);
#pragma unroll
    for (int i = 0; i < 16; ++i) {
      float p = __builtin_amdgcn_exp2f(accS[i] * SC + ccB[i]);
      __builtin_nontemporal_store(p, outB + (size_t)((i & 3) + 8 * (i >> 2)) * L_SEQ + s * 128);
    }
    ROT();
  }
#undef KLOAD
#undef ROT
}

// ---------------------------------------------------------------------------
extern "C" void kernel_launch(void* const* d_in, const int* in_sizes, int n_in,
                              void* d_out, int out_size, void* d_ws, size_t ws_size,
                              hipStream_t stream) {
  const float* X = (const float*)d_in[0];
  const float* W = (const float*)d_in[1];
  const float* bias = (const float*)d_in[2];
  float* out = (float*)d_out;
  char* ws = (char*)d_ws;
  _Float16* Wt = (_Float16*)ws;                       // 4 MB
  _Float16* Qh = (_Float16*)(ws + (4ull << 20));      // 8 MB
  _Float16* Kh = (_Float16*)(ws + (12ull << 20));     // 8 MB
  _Float16* X16 = (_Float16*)(ws + (20ull << 20));    // 8 MB (total 28 MB)

  xcast_kernel<<<2048, 256, 0, stream>>>(X, X16);
  wpack_kernel<<<dim3(64, 32), 256, 0, stream>>>(W, Wt);
  qk_gemm_kernel<<<1024, 256, 0, stream>>>(X16, Wt, bias, Qh, Kh);
  attn_softmax_kernel<<<1024, 256, 0, stream>>>(Qh, Kh, out);
}

// Round 12
// 168.422 us; speedup vs baseline: 4.6568x; 1.0017x over previous
//
#include <hip/hip_runtime.h>
#include <hip/hip_bf16.h>

typedef _Float16 half4v __attribute__((ext_vector_type(4)));
typedef _Float16 half8v __attribute__((ext_vector_type(8)));
typedef float float4v __attribute__((ext_vector_type(4)));
typedef float float16v __attribute__((ext_vector_type(16)));

#define L_SEQ 2048
#define EMB 1024
#define NH 16
#define DKV 64

__device__ inline void gll16(const void* g, void* l) {
  __builtin_amdgcn_global_load_lds((const __attribute__((address_space(1))) void*)g,
                                   (__attribute__((address_space(3))) void*)l, 16, 0, 0);
}

// ---------------------------------------------------------------------------
// Kernel A: cast X fp32 -> f16 (4096x1024), 8 elems/thread
// ---------------------------------------------------------------------------
__global__ __launch_bounds__(256) void xcast_kernel(const float* __restrict__ X,
                                                    _Float16* __restrict__ X16) {
  size_t i = ((size_t)blockIdx.x * 256 + threadIdx.x) * 8;
  float4v v0 = *(const float4v*)(X + i);
  float4v v1 = *(const float4v*)(X + i + 4);
  half8v h;
  h[0] = (_Float16)v0[0]; h[1] = (_Float16)v0[1]; h[2] = (_Float16)v0[2]; h[3] = (_Float16)v0[3];
  h[4] = (_Float16)v1[0]; h[5] = (_Float16)v1[1]; h[6] = (_Float16)v1[2]; h[7] = (_Float16)v1[3];
  *(half8v*)(X16 + i) = h;
}

// ---------------------------------------------------------------------------
// Kernel B: pack + transpose + cast W_qkv (fp32 [1024][3072]) -> Wt (f16 [2048][1024])
// ---------------------------------------------------------------------------
__global__ __launch_bounds__(256) void wpack_kernel(const float* __restrict__ W,
                                                    _Float16* __restrict__ Wt) {
  __shared__ float tile[32][33];
  int n0 = blockIdx.x * 32;
  int k0 = blockIdx.y * 32;
  int h = n0 >> 7;
  int wc = h * 192 + (n0 & 127);
  int tx = threadIdx.x & 31;
  int ty = threadIdx.x >> 5;
#pragma unroll
  for (int i = 0; i < 4; ++i) {
    int k = ty + i * 8;
    tile[k][tx] = W[(size_t)(k0 + k) * 3072 + wc + tx];
  }
  __syncthreads();
#pragma unroll
  for (int i = 0; i < 4; ++i) {
    int n = ty + i * 8;
    Wt[(size_t)(n0 + n) * 1024 + k0 + tx] = (_Float16)tile[tx][n];
  }
}

// ---------------------------------------------------------------------------
// Kernel C (v3): Q/K projection GEMM. BM=128, BN=64, BK=64; 1024 blocks
// (4/CU). Conflict-free XOR-granule LDS (validated R10: 30.6->21.1 us/copy).
// ---------------------------------------------------------------------------
__global__ __launch_bounds__(256, 4) void qk_gemm_kernel(const _Float16* __restrict__ X16,
                                                         const _Float16* __restrict__ Wt,
                                                         const float* __restrict__ bias,
                                                         _Float16* __restrict__ Qh,
                                                         _Float16* __restrict__ Kh) {
  __shared__ _Float16 As[128 * 64];  // 16 KB
  __shared__ _Float16 Bs[64 * 64];   // 8 KB
  int id = blockIdx.x;
  int xcd = id & 7;
  int rest = id >> 3;
  int n0 = (xcd * 4 + (rest & 3)) * 64;
  int m0 = (rest >> 2) * 128;
  int t = threadIdx.x;
  int l = t & 63;
  int wv = t >> 6;
  int wm = wv >> 1, wn = wv & 1;
  int cl = l & 15, hi = l >> 4;
  float4v acc[4][2] = {};
  for (int k0 = 0; k0 < 1024; k0 += 64) {
#pragma unroll
    for (int c = 0; c < 4; ++c) {
      int gi = (wv * 4 + c) * 64 + l;
      int r_ = gi >> 3, s_ = gi & 7;
      gll16(X16 + (size_t)(m0 + r_) * 1024 + k0 + 8 * (s_ ^ (r_ & 7)), &As[(wv * 4 + c) * 512]);
    }
#pragma unroll
    for (int c = 0; c < 2; ++c) {
      int gi = (wv * 2 + c) * 64 + l;
      int r_ = gi >> 3, s_ = gi & 7;
      gll16(Wt + (size_t)(n0 + r_) * 1024 + k0 + 8 * (s_ ^ (r_ & 7)), &Bs[(wv * 2 + c) * 512]);
    }
    __syncthreads();
#pragma unroll
    for (int kh = 0; kh < 2; ++kh) {
      int g = kh * 4 + hi;
      half8v a[4], b[2];
#pragma unroll
      for (int mt = 0; mt < 4; ++mt) {
        int row = wm * 64 + mt * 16 + cl;
        a[mt] = *(const half8v*)(&As[row * 64 + 8 * (g ^ (row & 7))]);
      }
#pragma unroll
      for (int nt = 0; nt < 2; ++nt) {
        int row = wn * 32 + nt * 16 + cl;
        b[nt] = *(const half8v*)(&Bs[row * 64 + 8 * (g ^ (row & 7))]);
      }
#pragma unroll
      for (int mt = 0; mt < 4; ++mt)
#pragma unroll
        for (int nt = 0; nt < 2; ++nt)
          acc[mt][nt] = __builtin_amdgcn_mfma_f32_16x16x32_f16(a[mt], b[nt], acc[mt][nt], 0, 0, 0);
    }
    __syncthreads();
  }
#pragma unroll
  for (int mt = 0; mt < 4; ++mt) {
#pragma unroll
    for (int nt = 0; nt < 2; ++nt) {
      int n_g = n0 + wn * 32 + nt * 16 + cl;
      int hh = n_g >> 7, rr = n_g & 127;
      float bv = bias[hh * 192 + rr];
      _Float16* dstbase = (rr < 64) ? Qh : Kh;
      int d = rr & 63;
#pragma unroll
      for (int r = 0; r < 4; ++r) {
        int row_g = m0 + wm * 64 + mt * 16 + hi * 4 + r;
        int bb = row_g >> 11, lr = row_g & 2047;
        dstbase[(((size_t)bb * NH + hh) * L_SEQ + lr) * DKV + d] = (_Float16)(acc[mt][nt][r] + bv);
      }
    }
  }
}

// ---------------------------------------------------------------------------
// Kernel D (v6.2): v6 base + (1) plain full-line stores instead of NT (L2
// write-combining; each half-wave store = one full 128B line), (2) 4-way
// partial sum accumulators breaking the 32-deep serial FP add chain in pass 1.
// ---------------------------------------------------------------------------
__global__ __launch_bounds__(256, 4) void attn_softmax_kernel(const _Float16* __restrict__ Qh,
                                                              const _Float16* __restrict__ Kh,
                                                              float* __restrict__ out) {
  __shared__ _Float16 Ks[2][128 * 64];  // 32 KB dbuf, granule-swizzled rows
  __shared__ float sums[4][32];
  int id = blockIdx.x;
  int xcd = id & 7;
  int rest = id >> 3;
  int rb = rest & 31;
  int bh = ((rest >> 5) << 3) + xcd;  // bijective XCD swizzle
  int t = threadIdx.x;
  int l = t & 63;
  int wv = t >> 6;
  int lj = l & 31;   // 32-lane index (q-col in pass1 / j-col in pass2)
  int hk = l >> 5;   // k-half
  int qh = wv & 1;   // q-half owned by this wave
  int jh = wv >> 1;  // j-half of each 128-step
  int qbase = rb * 64;
  const _Float16* Qb = Qh + ((size_t)bh * L_SEQ + qbase) * DKV;
  const _Float16* Kb = Kh + (size_t)bh * L_SEQ * DKV;
  const float SC = 0.18033688011112042f;  // log2(e)/sqrt(64)

  half8v bq[4];
#pragma unroll
  for (int ks = 0; ks < 4; ++ks)
    bq[ks] = *(const half8v*)(Qb + (size_t)(qh * 32 + lj) * DKV + ks * 16 + hk * 8);

#define STAGE(bufi, j0)                                                     \
  {                                                                         \
    _Pragma("unroll") for (int c = 0; c < 4; ++c) {                         \
      int gi = (wv * 4 + c) * 64 + l;                                       \
      int r_ = gi >> 3, s_ = gi & 7;                                        \
      gll16(Kb + (size_t)((j0) + r_) * DKV + 8 * (s_ ^ (r_ & 7)),           \
            &Ks[bufi][(wv * 4 + c) * 512]);                                 \
    }                                                                       \
  }

  // ---- Pass 1: row sums.  mfma(A=K, B=Q): D col = q (lj), rows = j ----
  float ls[4] = {0.f, 0.f, 0.f, 0.f};  // 4-way partials: break serial add chain
  int buf = 0;
  STAGE(0, 0);
  __syncthreads();
  for (int s = 0; s < 16; ++s) {
    if (s + 1 < 16) STAGE(buf ^ 1, (s + 1) * 128);
#pragma unroll
    for (int q2 = 0; q2 < 2; ++q2) {
      int jq = jh * 2 + q2;
      int krow = jq * 32 + lj;
      half8v bk[4];
#pragma unroll
      for (int ks = 0; ks < 4; ++ks)
        bk[ks] = *(const half8v*)(&Ks[buf][krow * 64 + 8 * ((2 * ks + hk) ^ (krow & 7))]);
      float16v acc = {};
#pragma unroll
      for (int ks = 0; ks < 4; ++ks)
        acc = __builtin_amdgcn_mfma_f32_32x32x16_f16(bk[ks], bq[ks], acc, 0, 0, 0);
#pragma unroll
      for (int i = 0; i < 16; ++i) ls[i & 3] += __builtin_amdgcn_exp2f(acc[i] * SC);
    }
    __syncthreads();
    buf ^= 1;
  }
  float lsum = (ls[0] + ls[1]) + (ls[2] + ls[3]);
  lsum += __shfl_xor(lsum, 32);
  if (l < 32) sums[wv][lj] = lsum;
  __syncthreads();

  float cc[16];
#pragma unroll
  for (int i = 0; i < 16; ++i) {
    int qo = (i & 3) + 8 * (i >> 2) + 4 * hk;
    cc[i] = -__log2f(sums[qh][qo] + sums[qh + 2][qo]);
  }

  // ---- Pass 2: recompute, mfma(A=Q, B=K): D col = j (lj), rows = q ----
  size_t orow0 = ((size_t)bh * L_SEQ + qbase + qh * 32) * L_SEQ;
  STAGE(0, 0);
  __syncthreads();
  buf = 0;
  for (int s = 0; s < 16; ++s) {
    if (s + 1 < 16) STAGE(buf ^ 1, (s + 1) * 128);
#pragma unroll
    for (int q2 = 0; q2 < 2; ++q2) {
      int jq = jh * 2 + q2;
      int krow = jq * 32 + lj;
      half8v bk[4];
#pragma unroll
      for (int ks = 0; ks < 4; ++ks)
        bk[ks] = *(const half8v*)(&Ks[buf][krow * 64 + 8 * ((2 * ks + hk) ^ (krow & 7))]);
      float16v acc = {};
#pragma unroll
      for (int ks = 0; ks < 4; ++ks)
        acc = __builtin_amdgcn_mfma_f32_32x32x16_f16(bq[ks], bk[ks], acc, 0, 0, 0);
      size_t col = (size_t)s * 128 + jq * 32 + lj;
#pragma unroll
      for (int i = 0; i < 16; ++i) {
        float p = __builtin_amdgcn_exp2f(acc[i] * SC + cc[i]);
        int qo = (i & 3) + 8 * (i >> 2) + 4 * hk;
        out[orow0 + (size_t)qo * L_SEQ + col] = p;  // plain store: L2 write-combine
      }
    }
    __syncthreads();
    buf ^= 1;
  }
#undef STAGE
}

// ---------------------------------------------------------------------------
extern "C" void kernel_launch(void* const* d_in, const int* in_sizes, int n_in,
                              void* d_out, int out_size, void* d_ws, size_t ws_size,
                              hipStream_t stream) {
  const float* X = (const float*)d_in[0];
  const float* W = (const float*)d_in[1];
  const float* bias = (const float*)d_in[2];
  float* out = (float*)d_out;
  char* ws = (char*)d_ws;
  _Float16* Wt = (_Float16*)ws;                       // 4 MB
  _Float16* Qh = (_Float16*)(ws + (4ull << 20));      // 8 MB
  _Float16* Kh = (_Float16*)(ws + (12ull << 20));     // 8 MB
  _Float16* X16 = (_Float16*)(ws + (20ull << 20));    // 8 MB (total 28 MB)

  xcast_kernel<<<2048, 256, 0, stream>>>(X, X16);
  wpack_kernel<<<dim3(64, 32), 256, 0, stream>>>(W, Wt);
  qk_gemm_kernel<<<1024, 256, 0, stream>>>(X16, Wt, bias, Qh, Kh);
  attn_softmax_kernel<<<1024, 256, 0, stream>>>(Qh, Kh, out);
}

// Round 13
// 161.278 us; speedup vs baseline: 4.8630x; 1.0443x over previous
//
#include <hip/hip_runtime.h>
#include <hip/hip_bf16.h>

typedef _Float16 half4v __attribute__((ext_vector_type(4)));
typedef _Float16 half8v __attribute__((ext_vector_type(8)));
typedef float float4v __attribute__((ext_vector_type(4)));
typedef float float16v __attribute__((ext_vector_type(16)));

#define L_SEQ 2048
#define EMB 1024
#define NH 16
#define DKV 64

__device__ inline void gll16(const void* g, void* l) {
  __builtin_amdgcn_global_load_lds((const __attribute__((address_space(1))) void*)g,
                                   (__attribute__((address_space(3))) void*)l, 16, 0, 0);
}

// ---------------------------------------------------------------------------
// Kernel A: cast X fp32 -> f16 (4096x1024), 8 elems/thread
// ---------------------------------------------------------------------------
__global__ __launch_bounds__(256) void xcast_kernel(const float* __restrict__ X,
                                                    _Float16* __restrict__ X16) {
  size_t i = ((size_t)blockIdx.x * 256 + threadIdx.x) * 8;
  float4v v0 = *(const float4v*)(X + i);
  float4v v1 = *(const float4v*)(X + i + 4);
  half8v h;
  h[0] = (_Float16)v0[0]; h[1] = (_Float16)v0[1]; h[2] = (_Float16)v0[2]; h[3] = (_Float16)v0[3];
  h[4] = (_Float16)v1[0]; h[5] = (_Float16)v1[1]; h[6] = (_Float16)v1[2]; h[7] = (_Float16)v1[3];
  *(half8v*)(X16 + i) = h;
}

// ---------------------------------------------------------------------------
// Kernel B: pack + transpose + cast W_qkv (fp32 [1024][3072]) -> Wt (f16 [2048][1024])
// ---------------------------------------------------------------------------
__global__ __launch_bounds__(256) void wpack_kernel(const float* __restrict__ W,
                                                    _Float16* __restrict__ Wt) {
  __shared__ float tile[32][33];
  int n0 = blockIdx.x * 32;
  int k0 = blockIdx.y * 32;
  int h = n0 >> 7;
  int wc = h * 192 + (n0 & 127);
  int tx = threadIdx.x & 31;
  int ty = threadIdx.x >> 5;
#pragma unroll
  for (int i = 0; i < 4; ++i) {
    int k = ty + i * 8;
    tile[k][tx] = W[(size_t)(k0 + k) * 3072 + wc + tx];
  }
  __syncthreads();
#pragma unroll
  for (int i = 0; i < 4; ++i) {
    int n = ty + i * 8;
    Wt[(size_t)(n0 + n) * 1024 + k0 + tx] = (_Float16)tile[tx][n];
  }
}

// ---------------------------------------------------------------------------
// Kernel C (v3): Q/K projection GEMM. BM=128, BN=64, BK=64; 1024 blocks
// (4/CU). Conflict-free XOR-granule LDS (validated R10: 30.6->21.1 us/copy).
// ---------------------------------------------------------------------------
__global__ __launch_bounds__(256, 4) void qk_gemm_kernel(const _Float16* __restrict__ X16,
                                                         const _Float16* __restrict__ Wt,
                                                         const float* __restrict__ bias,
                                                         _Float16* __restrict__ Qh,
                                                         _Float16* __restrict__ Kh) {
  __shared__ _Float16 As[128 * 64];  // 16 KB
  __shared__ _Float16 Bs[64 * 64];   // 8 KB
  int id = blockIdx.x;
  int xcd = id & 7;
  int rest = id >> 3;
  int n0 = (xcd * 4 + (rest & 3)) * 64;
  int m0 = (rest >> 2) * 128;
  int t = threadIdx.x;
  int l = t & 63;
  int wv = t >> 6;
  int wm = wv >> 1, wn = wv & 1;
  int cl = l & 15, hi = l >> 4;
  float4v acc[4][2] = {};
  for (int k0 = 0; k0 < 1024; k0 += 64) {
#pragma unroll
    for (int c = 0; c < 4; ++c) {
      int gi = (wv * 4 + c) * 64 + l;
      int r_ = gi >> 3, s_ = gi & 7;
      gll16(X16 + (size_t)(m0 + r_) * 1024 + k0 + 8 * (s_ ^ (r_ & 7)), &As[(wv * 4 + c) * 512]);
    }
#pragma unroll
    for (int c = 0; c < 2; ++c) {
      int gi = (wv * 2 + c) * 64 + l;
      int r_ = gi >> 3, s_ = gi & 7;
      gll16(Wt + (size_t)(n0 + r_) * 1024 + k0 + 8 * (s_ ^ (r_ & 7)), &Bs[(wv * 2 + c) * 512]);
    }
    __syncthreads();
#pragma unroll
    for (int kh = 0; kh < 2; ++kh) {
      int g = kh * 4 + hi;
      half8v a[4], b[2];
#pragma unroll
      for (int mt = 0; mt < 4; ++mt) {
        int row = wm * 64 + mt * 16 + cl;
        a[mt] = *(const half8v*)(&As[row * 64 + 8 * (g ^ (row & 7))]);
      }
#pragma unroll
      for (int nt = 0; nt < 2; ++nt) {
        int row = wn * 32 + nt * 16 + cl;
        b[nt] = *(const half8v*)(&Bs[row * 64 + 8 * (g ^ (row & 7))]);
      }
#pragma unroll
      for (int mt = 0; mt < 4; ++mt)
#pragma unroll
        for (int nt = 0; nt < 2; ++nt)
          acc[mt][nt] = __builtin_amdgcn_mfma_f32_16x16x32_f16(a[mt], b[nt], acc[mt][nt], 0, 0, 0);
    }
    __syncthreads();
  }
#pragma unroll
  for (int mt = 0; mt < 4; ++mt) {
#pragma unroll
    for (int nt = 0; nt < 2; ++nt) {
      int n_g = n0 + wn * 32 + nt * 16 + cl;
      int hh = n_g >> 7, rr = n_g & 127;
      float bv = bias[hh * 192 + rr];
      _Float16* dstbase = (rr < 64) ? Qh : Kh;
      int d = rr & 63;
#pragma unroll
      for (int r = 0; r < 4; ++r) {
        int row_g = m0 + wm * 64 + mt * 16 + hi * 4 + r;
        int bb = row_g >> 11, lr = row_g & 2047;
        dstbase[(((size_t)bb * NH + hh) * L_SEQ + lr) * DKV + d] = (_Float16)(acc[mt][nt][r] + bv);
      }
    }
  }
}

// ---------------------------------------------------------------------------
// Kernel D (v9): hybrid. Pass 1 = v6 (LDS dbuf staging, mfma(K,Q) sums).
// Pass 2 = BARRIER-FREE: K fragments per-lane direct from L2 (panel warmed by
// pass 1), no LDS, no __syncthreads in the store loop -> NT stores stream
// continuously, throttled only by the vmcnt queue (smooth, BW-matched).
// ---------------------------------------------------------------------------
__global__ __launch_bounds__(256, 4) void attn_softmax_kernel(const _Float16* __restrict__ Qh,
                                                              const _Float16* __restrict__ Kh,
                                                              float* __restrict__ out) {
  __shared__ _Float16 Ks[2][128 * 64];  // 32 KB dbuf, granule-swizzled rows
  __shared__ float sums[4][32];
  int id = blockIdx.x;
  int xcd = id & 7;
  int rest = id >> 3;
  int rb = rest & 31;
  int bh = ((rest >> 5) << 3) + xcd;  // bijective XCD swizzle
  int t = threadIdx.x;
  int l = t & 63;
  int wv = t >> 6;
  int lj = l & 31;   // 32-lane index (q-col in pass1 / j-col in pass2)
  int hk = l >> 5;   // k-half
  int qh = wv & 1;   // q-half owned by this wave
  int jh = wv >> 1;  // j-half of each 128-step
  int qbase = rb * 64;
  const _Float16* Qb = Qh + ((size_t)bh * L_SEQ + qbase) * DKV;
  const _Float16* Kb = Kh + (size_t)bh * L_SEQ * DKV;
  const float SC = 0.18033688011112042f;  // log2(e)/sqrt(64)

  half8v bq[4];
#pragma unroll
  for (int ks = 0; ks < 4; ++ks)
    bq[ks] = *(const half8v*)(Qb + (size_t)(qh * 32 + lj) * DKV + ks * 16 + hk * 8);

#define STAGE(bufi, j0)                                                     \
  {                                                                         \
    _Pragma("unroll") for (int c = 0; c < 4; ++c) {                         \
      int gi = (wv * 4 + c) * 64 + l;                                       \
      int r_ = gi >> 3, s_ = gi & 7;                                        \
      gll16(Kb + (size_t)((j0) + r_) * DKV + 8 * (s_ ^ (r_ & 7)),           \
            &Ks[bufi][(wv * 4 + c) * 512]);                                 \
    }                                                                       \
  }

  // ---- Pass 1 (v6): row sums. mfma(A=K, B=Q): D col = q (lj), rows = j ----
  float ls[4] = {0.f, 0.f, 0.f, 0.f};  // 4-way partials: break serial add chain
  int buf = 0;
  STAGE(0, 0);
  __syncthreads();
  for (int s = 0; s < 16; ++s) {
    if (s + 1 < 16) STAGE(buf ^ 1, (s + 1) * 128);
#pragma unroll
    for (int q2 = 0; q2 < 2; ++q2) {
      int jq = jh * 2 + q2;
      int krow = jq * 32 + lj;
      half8v bk[4];
#pragma unroll
      for (int ks = 0; ks < 4; ++ks)
        bk[ks] = *(const half8v*)(&Ks[buf][krow * 64 + 8 * ((2 * ks + hk) ^ (krow & 7))]);
      float16v acc = {};
#pragma unroll
      for (int ks = 0; ks < 4; ++ks)
        acc = __builtin_amdgcn_mfma_f32_32x32x16_f16(bk[ks], bq[ks], acc, 0, 0, 0);
#pragma unroll
      for (int i = 0; i < 16; ++i) ls[i & 3] += __builtin_amdgcn_exp2f(acc[i] * SC);
    }
    __syncthreads();
    buf ^= 1;
  }
  float lsum = (ls[0] + ls[1]) + (ls[2] + ls[3]);
  lsum += __shfl_xor(lsum, 32);
  if (l < 32) sums[wv][lj] = lsum;
  __syncthreads();

  float cc[16];
#pragma unroll
  for (int i = 0; i < 16; ++i) {
    int qo = (i & 3) + 8 * (i >> 2) + 4 * hk;
    cc[i] = -__log2f(sums[qh][qo] + sums[qh + 2][qo]);
  }

  // ---- Pass 2 (barrier-free): K direct from L2, mfma(A=Q, B=K), NT stores ----
  size_t orow0 = ((size_t)bh * L_SEQ + qbase + qh * 32) * L_SEQ;
  for (int s = 0; s < 16; ++s) {
#pragma unroll
    for (int q2 = 0; q2 < 2; ++q2) {
      int jq = jh * 2 + q2;
      int jrow = s * 128 + jq * 32 + lj;  // this lane's K row (L2-resident)
      const _Float16* Kp = Kb + (size_t)jrow * DKV + hk * 8;
      half8v bk[4];
#pragma unroll
      for (int ks = 0; ks < 4; ++ks) bk[ks] = *(const half8v*)(Kp + ks * 16);
      float16v acc = {};
#pragma unroll
      for (int ks = 0; ks < 4; ++ks)
        acc = __builtin_amdgcn_mfma_f32_32x32x16_f16(bq[ks], bk[ks], acc, 0, 0, 0);
      size_t col = (size_t)s * 128 + jq * 32 + lj;
#pragma unroll
      for (int i = 0; i < 16; ++i) {
        float p = __builtin_amdgcn_exp2f(acc[i] * SC + cc[i]);
        int qo = (i & 3) + 8 * (i >> 2) + 4 * hk;
        __builtin_nontemporal_store(p, out + orow0 + (size_t)qo * L_SEQ + col);
      }
    }
  }
#undef STAGE
}

// ---------------------------------------------------------------------------
extern "C" void kernel_launch(void* const* d_in, const int* in_sizes, int n_in,
                              void* d_out, int out_size, void* d_ws, size_t ws_size,
                              hipStream_t stream) {
  const float* X = (const float*)d_in[0];
  const float* W = (const float*)d_in[1];
  const float* bias = (const float*)d_in[2];
  float* out = (float*)d_out;
  char* ws = (char*)d_ws;
  _Float16* Wt = (_Float16*)ws;                       // 4 MB
  _Float16* Qh = (_Float16*)(ws + (4ull << 20));      // 8 MB
  _Float16* Kh = (_Float16*)(ws + (12ull << 20));     // 8 MB
  _Float16* X16 = (_Float16*)(ws + (20ull << 20));    // 8 MB (total 28 MB)

  xcast_kernel<<<2048, 256, 0, stream>>>(X, X16);
  wpack_kernel<<<dim3(64, 32), 256, 0, stream>>>(W, Wt);
  qk_gemm_kernel<<<1024, 256, 0, stream>>>(X16, Wt, bias, Qh, Kh);
  attn_softmax_kernel<<<1024, 256, 0, stream>>>(Qh, Kh, out);
}